// Round 2
// baseline (308.379 us; speedup 1.0000x reference)
//
#include <hip/hip_runtime.h>
#include <hip/hip_bf16.h>
#include <cstdint>
#include <cstddef>

#define B_  4
#define T_  2048
#define C_  1024
#define H_  16
#define D_  64
#define MROWS (B_*T_)      // 8192
#define NDIM  (H_*D_)      // 1024

typedef float  f32x4 __attribute__((ext_vector_type(4)));
typedef __bf16 bfrag __attribute__((ext_vector_type(8)));

__device__ __forceinline__ unsigned short f2bf(float f) {
  union { float f; unsigned u; } v; v.f = f;
  unsigned r = v.u + 0x7fffu + ((v.u >> 16) & 1u);
  return (unsigned short)(r >> 16);
}

__device__ __forceinline__ void async_load16(const void* g, void* l) {
  __builtin_amdgcn_global_load_lds((__attribute__((address_space(1))) void*)(void*)g,
                                   (__attribute__((address_space(3))) void*)l,
                                   16, 0, 0);
}

// pack two f32 -> two bf16 (round-half-up) in one u32
__device__ __forceinline__ unsigned pack_bf2(float f0, float f1) {
  unsigned a0 = __float_as_uint(f0) + 0x8000u;
  unsigned a1 = __float_as_uint(f1) + 0x8000u;
  return __builtin_amdgcn_perm(a1, a0, 0x07060302u);
}

// ---------------- fused prep: cvt q/k/v -> bf16, transpose Wq/Wk/Wv, Wo ----
// blocks [0,24576): cvt.  [24576,25344): wqkv transpose.  [25344,25600): wo.
__global__ __launch_bounds__(256) void prep_kernel(
    const float* __restrict__ q, const float* __restrict__ k, const float* __restrict__ v,
    unsigned short* __restrict__ qb, unsigned short* __restrict__ kb, unsigned short* __restrict__ vb,
    const float* __restrict__ Wq, const float* __restrict__ Wk, const float* __restrict__ Wv,
    unsigned short* __restrict__ wqT, unsigned short* __restrict__ wkT, unsigned short* __restrict__ wvT,
    const float* __restrict__ Wo, unsigned short* __restrict__ woT)
{
  const int id = blockIdx.x, tid = threadIdx.x;
  if (id < 24576) {
    int z = id >> 13, blk = id & 8191;
    const float* in = z == 0 ? q : z == 1 ? k : v;
    unsigned short* out = z == 0 ? qb : z == 1 ? kb : vb;
    int i = (blk * 256 + tid) * 4;
    float4 vv = *(const float4*)(in + i);
    ushort4 r;
    r.x = f2bf(vv.x); r.y = f2bf(vv.y); r.z = f2bf(vv.z); r.w = f2bf(vv.w);
    *(ushort4*)(out + i) = r;
  } else if (id < 25344) {
    int u = id - 24576;
    int z = u >> 4, cblk = u & 15;
    int sel = z >> 4, h = z & 15;
    const float* in = (sel == 0 ? Wq : sel == 1 ? Wk : Wv) + (size_t)h * C_ * D_; // [C][D]
    unsigned short* out = (sel == 0 ? wqT : sel == 1 ? wkT : wvT) + (size_t)h * D_ * C_; // [D][C]
    __shared__ float tile[64][65];
    int c0 = cblk * 64;
    int x = tid & 63, y4 = tid >> 6;
    for (int r = y4; r < 64; r += 4)
      tile[r][x] = in[(size_t)(c0 + r) * D_ + x];
    __syncthreads();
    for (int r = y4; r < 64; r += 4)
      out[(size_t)r * C_ + c0 + x] = f2bf(tile[x][r]);
  } else {
    int u = id - 25344;
    __shared__ float tile[64][65];
    int i0 = (u >> 4) * 64, j0 = (u & 15) * 64;
    int x = tid & 63, y4 = tid >> 6;
    for (int r = y4; r < 64; r += 4)
      tile[r][x] = Wo[(size_t)(i0 + r) * C_ + j0 + x];
    __syncthreads();
    for (int r = y4; r < 64; r += 4)
      woT[(size_t)(j0 + r) * NDIM + i0 + x] = f2bf(tile[x][r]);
  }
}

// ---------------- QKV projection: 256x256-tile 8-phase GEMM ----------------
// C[M=8192, N=1024] = A[M,K=1024] * Bt[N,K]^T  for z in {q,k,v}.
// 384 blocks x 512 threads, 8 waves (2x4), per-wave 128x64 output.
// LDS 128 KiB: As/Bs each 2 dbuf x 256x64 bf16 (chunk-XOR swizzled).
//
// Burst-early restage map (each slot restaged at earliest legal phase =
// 1 barrier-separated phase after its last read):
//   ph2: buf0.Ah0,Bh0 <- k0+2   ph3: buf0.Bh1 <- k0+2   ph4: buf0.Ah1 <- k0+2
//   ph6: buf1.Ah0,Bh0 <- k0+3   ph7: buf1.Bh1 <- k0+3   ph8: buf1.Ah1 <- k0+3
// One K-tile's stages = 8 loads/thread.  vmcnt(8) at ph4/ph8 FIFO-drains
// exactly the previous K-tile's 8 loads (binding drain issued 4+ phases
// earlier, ~600+ cy of cover) and never touches the newest K-tile's loads.
//   ph4 wait: outstanding prev{ph6x2,ph7,ph8}+cur{ph2x2,ph3,ph4}=16 -> 8
//             completes prev ph6-8 = buf1 slots read at ph5-7.   [verified]
//   ph8 wait: completes cur ph2-4 = buf0 slots read at next ph1-3. [verified]
__global__ __launch_bounds__(512, 2) void gemm_qkv_256(
    const unsigned short* __restrict__ A0, const unsigned short* __restrict__ A1, const unsigned short* __restrict__ A2,
    const unsigned short* __restrict__ B0t, const unsigned short* __restrict__ B1t, const unsigned short* __restrict__ B2t,
    void* C0, void* C1, void* C2)
{
  constexpr int K = C_;     // 1024
  constexpr int N = NDIM;   // 1024
  __shared__ __align__(16) short As[2 * 16384];   // [buf][256 rows][64 c], 32KB/buf
  __shared__ __align__(16) short Bs[2 * 16384];

  const int id = blockIdx.x;
  const int xcd = id & 7, s = id >> 3;            // s in [0,48)
  const int z = s >> 4, t = s & 15;
  const int mb = xcd * 4 + (t >> 2), nb = t & 3;  // nb fastest: A-panel L2 reuse per XCD
  const int m0 = mb * 256, n0 = nb * 256;

  const unsigned short* A  = z == 0 ? A0 : z == 1 ? A1 : A2;
  const unsigned short* Bt = z == 0 ? B0t : z == 1 ? B1t : B2t;

  const int tid = threadIdx.x, lane = tid & 63;
  const int quad = lane >> 4, l15 = lane & 15;
  const int wave = tid >> 6;
  const int qr = wave >> 2, qc = wave & 3;        // wave sub-tile inside a 128x128 quadrant
  const int wbase = tid & ~63;                    // wave-uniform

  f32x4 acc[2][2][4][2] = {};                     // [QR][QC][i(4x16 rows)][j(2x16 cols)]

  // stage one half-tile (128 rows x 64 c = 1024 chunks; 2 chunks/thread).
  // LDS dest linear (wave-uniform base), global source pre-swizzled (chunk XOR).
  auto stageA = [&](int buf, int kt, int h) {
#pragma unroll
    for (int i2 = 0; i2 < 2; ++i2) {
      int p0 = h * 1024 + i2 * 512 + wbase;
      int p  = p0 + lane;
      int m  = p >> 3, cl = (p & 7) ^ (m & 7);
      async_load16(A + (size_t)(m0 + m) * K + kt * 64 + cl * 8,
                   (char*)As + buf * 32768 + p0 * 16);
    }
  };
  auto stageB = [&](int buf, int kt, int h) {
#pragma unroll
    for (int i2 = 0; i2 < 2; ++i2) {
      int p0 = h * 1024 + i2 * 512 + wbase;
      int p  = p0 + lane;
      int m  = p >> 3, cl = (p & 7) ^ (m & 7);
      async_load16(Bt + (size_t)(n0 + m) * K + kt * 64 + cl * 8,
                   (char*)Bs + buf * 32768 + p0 * 16);
    }
  };

  bfrag a[2][4];        // A frags for current quadrant-row
  bfrag b[2][2];        // B frags QC=0
  bfrag b2[2][2];       // B frags QC=1

  auto ldA = [&](int buf, int QR) {
#pragma unroll
    for (int ks = 0; ks < 2; ++ks)
#pragma unroll
      for (int i = 0; i < 4; ++i) {
        int row = QR * 128 + qr * 64 + i * 16 + l15;
        int c = (ks * 4 + quad) ^ (row & 7);
        a[ks][i] = *(const bfrag*)(As + buf * 16384 + row * 64 + c * 8);
      }
  };
  auto ldB = [&](bfrag (&bb)[2][2], int buf, int QC) {
#pragma unroll
    for (int ks = 0; ks < 2; ++ks)
#pragma unroll
      for (int j = 0; j < 2; ++j) {
        int col = QC * 128 + qc * 32 + j * 16 + l15;
        int c = (ks * 4 + quad) ^ (col & 7);
        bb[ks][j] = *(const bfrag*)(Bs + buf * 16384 + col * 64 + c * 8);
      }
  };
  auto mm = [&](f32x4 (&ac)[4][2], bfrag (&bb)[2][2]) {
    __builtin_amdgcn_s_setprio(1);
#pragma unroll
    for (int ks = 0; ks < 2; ++ks)
#pragma unroll
      for (int i = 0; i < 4; ++i)
#pragma unroll
        for (int j = 0; j < 2; ++j)
          ac[i][j] = __builtin_amdgcn_mfma_f32_16x16x32_bf16(a[ks][i], bb[ks][j], ac[i][j], 0, 0, 0);
    __builtin_amdgcn_s_setprio(0);
  };

#define PH_BAR() __builtin_amdgcn_s_barrier()
#define PH_LGK() asm volatile("s_waitcnt lgkmcnt(0)" ::: "memory")

  // ---- prologue: stage kt0 (buf0) + kt1 (buf1) fully; drain kt0 only ------
  stageA(0, 0, 0); stageB(0, 0, 0); stageB(0, 0, 1); stageA(0, 0, 1);
  stageA(1, 1, 0); stageB(1, 1, 0); stageB(1, 1, 1); stageA(1, 1, 1);
  asm volatile("s_waitcnt vmcnt(8)" ::: "memory");   // kt0 landed; kt1 (8 loads) in flight
  PH_BAR();

  // ---- main loop: kt = k0 (buf0) then k0+1 (buf1); stages k0+2, k0+3 ------
#pragma unroll 1
  for (int k0 = 0; k0 <= 12; k0 += 2) {
    // ph1: Q00 of k0 (reads buf0.Ah0 + Bh0)
    ldA(0, 0); ldB(b, 0, 0);
    PH_BAR(); PH_LGK(); mm(acc[0][0], b); PH_BAR();
    // ph2: Q01 (reads buf0.Bh1); burst-stage buf0.Ah0+Bh0 <- k0+2
    ldB(b2, 0, 1);
    stageA(0, k0 + 2, 0); stageB(0, k0 + 2, 0);
    PH_BAR(); PH_LGK(); mm(acc[0][1], b2); PH_BAR();
    // ph3: Q10 (reads buf0.Ah1); stage buf0.Bh1 <- k0+2
    ldA(0, 1);
    stageB(0, k0 + 2, 1);
    PH_BAR(); PH_LGK(); mm(acc[1][0], b); PH_BAR();
    // ph4: Q11; stage buf0.Ah1 <- k0+2; counted wait drains kt(k0+1) stages
    stageA(0, k0 + 2, 1);
    PH_BAR(); PH_LGK(); mm(acc[1][1], b2);
    asm volatile("s_waitcnt vmcnt(8)" ::: "memory");
    PH_BAR();
    // ph5: Q00 of k0+1 (reads buf1.Ah0 + Bh0)
    ldA(1, 0); ldB(b, 1, 0);
    PH_BAR(); PH_LGK(); mm(acc[0][0], b); PH_BAR();
    // ph6: Q01 (reads buf1.Bh1); burst-stage buf1.Ah0+Bh0 <- k0+3
    ldB(b2, 1, 1);
    stageA(1, k0 + 3, 0); stageB(1, k0 + 3, 0);
    PH_BAR(); PH_LGK(); mm(acc[0][1], b2); PH_BAR();
    // ph7: Q10 (reads buf1.Ah1); stage buf1.Bh1 <- k0+3
    ldA(1, 1);
    stageB(1, k0 + 3, 1);
    PH_BAR(); PH_LGK(); mm(acc[1][0], b); PH_BAR();
    // ph8: Q11; stage buf1.Ah1 <- k0+3; counted wait drains kt(k0+2) stages
    stageA(1, k0 + 3, 1);
    PH_BAR(); PH_LGK(); mm(acc[1][1], b2);
    asm volatile("s_waitcnt vmcnt(8)" ::: "memory");
    PH_BAR();
  }

  // ---- epilogue: kt14 (buf0, already drained), kt15 (buf1) ----------------
  ldA(0, 0); ldB(b, 0, 0);
  PH_BAR(); PH_LGK(); mm(acc[0][0], b); PH_BAR();
  ldB(b2, 0, 1);
  PH_BAR(); PH_LGK(); mm(acc[0][1], b2); PH_BAR();
  ldA(0, 1);
  PH_BAR(); PH_LGK(); mm(acc[1][0], b); PH_BAR();
  mm(acc[1][1], b2);
  asm volatile("s_waitcnt vmcnt(0)" ::: "memory");   // kt15 fully landed
  PH_BAR();
  ldA(1, 0); ldB(b, 1, 0);
  PH_LGK(); mm(acc[0][0], b);
  ldB(b2, 1, 1);
  PH_LGK(); mm(acc[0][1], b2);
  ldA(1, 1);
  PH_LGK(); mm(acc[1][0], b);
  mm(acc[1][1], b2);

#undef PH_BAR
#undef PH_LGK

  // ---- C write ----
  void* Cv = z == 0 ? C0 : z == 1 ? C1 : C2;
  if (z < 2) {
    unsigned short* Cb = (unsigned short*)Cv;
#pragma unroll
    for (int QR = 0; QR < 2; ++QR)
#pragma unroll
      for (int QC = 0; QC < 2; ++QC)
#pragma unroll
        for (int i = 0; i < 4; ++i) {
          int row0 = m0 + QR * 128 + qr * 64 + i * 16 + quad * 4;
#pragma unroll
          for (int j = 0; j < 2; ++j) {
            int col = n0 + QC * 128 + qc * 32 + j * 16 + l15;
#pragma unroll
            for (int r = 0; r < 4; ++r)
              Cb[(size_t)(row0 + r) * N + col] = f2bf(acc[QR][QC][i][j][r]);
          }
        }
  } else {
    unsigned short* Vo = (unsigned short*)Cv;
#pragma unroll
    for (int QR = 0; QR < 2; ++QR)
#pragma unroll
      for (int QC = 0; QC < 2; ++QC)
#pragma unroll
        for (int i = 0; i < 4; ++i) {
          int m = m0 + QR * 128 + qr * 64 + i * 16 + quad * 4;  // token, 4 consecutive
          int bb = m >> 11, tt = m & 2047;
#pragma unroll
          for (int j = 0; j < 2; ++j) {
            int n = n0 + QC * 128 + qc * 32 + j * 16 + l15;
            int hh = n >> 6, dd = n & 63;
            ushort4 pk;
            pk.x = f2bf(acc[QR][QC][i][j][0]); pk.y = f2bf(acc[QR][QC][i][j][1]);
            pk.z = f2bf(acc[QR][QC][i][j][2]); pk.w = f2bf(acc[QR][QC][i][j][3]);
            *(ushort4*)(Vo + (((size_t)bb * 16 + hh) * 64 + dd) * T_ + tt) = pk;
          }
        }
  }
}

// ---------------- GEMM: C[M,N] = A[M,K] * Bt[N,K]^T  (bf16 in, fp32 acc) ----
// (retained for the output projection, EPI=1 only)
template <int EPI>
__global__ __launch_bounds__(256) void gemm_bt_kernel(
    const unsigned short* __restrict__ A0, const unsigned short* __restrict__ A1, const unsigned short* __restrict__ A2,
    const unsigned short* __restrict__ B0, const unsigned short* __restrict__ B1, const unsigned short* __restrict__ B2,
    void* C0, void* C1, void* C2, const float* __restrict__ bias,
    int M, int N, int K)
{
  const int id = blockIdx.x;
  const int xcd = id & 7, s = id >> 3;
  const int z = s >> 6;            // 8 m-blocks x 8 n-blocks = 64 slots per XCD per z
  const int t = s & 63;
  const int mb = xcd * 8 + (t >> 3);
  const int nb = t & 7;

  const unsigned short* A  = z == 0 ? A0 : z == 1 ? A1 : A2;
  const unsigned short* Bt = z == 0 ? B0 : z == 1 ? B1 : B2;
  void* Cv                 = z == 0 ? C0 : z == 1 ? C1 : C2;

  __shared__ __align__(16) short As[128 * 64];
  __shared__ __align__(16) short Bs[128 * 64];

  const int tid = threadIdx.x, lane = tid & 63, wave = tid >> 6;
  const int quad = lane >> 4, l15 = lane & 15;
  const int m0 = mb * 128, n0 = nb * 128;
  const int wm = (wave >> 1) * 64, wn = (wave & 1) * 64;

  f32x4 acc[4][4] = {};

  for (int k0 = 0; k0 < K; k0 += 64) {
#pragma unroll
    for (int i = 0; i < 4; ++i) {
      int p0 = (wave * 4 + i) * 64;
      int p = p0 + lane;
      int m = p >> 3, cl = (p & 7) ^ (m & 7);
      async_load16(A  + (size_t)(m0 + m) * K + k0 + cl * 8, (char*)As + p0 * 16);
      async_load16(Bt + (size_t)(n0 + m) * K + k0 + cl * 8, (char*)Bs + p0 * 16);
    }
    __syncthreads();
#pragma unroll
    for (int ks = 0; ks < 2; ++ks) {
      bfrag af[4], bf[4];
#pragma unroll
      for (int i = 0; i < 4; ++i) {
        int m = wm + i * 16 + l15;
        int c = (ks * 4 + quad) ^ (m & 7);
        af[i] = *(const bfrag*)(As + m * 64 + c * 8);
        int n = wn + i * 16 + l15;
        int c2 = (ks * 4 + quad) ^ (n & 7);
        bf[i] = *(const bfrag*)(Bs + n * 64 + c2 * 8);
      }
#pragma unroll
      for (int i = 0; i < 4; ++i)
#pragma unroll
        for (int j = 0; j < 4; ++j)
          acc[i][j] = __builtin_amdgcn_mfma_f32_16x16x32_bf16(af[i], bf[j], acc[i][j], 0, 0, 0);
    }
    __syncthreads();
  }

  if constexpr (EPI == 0) {
    if (z < 2) {
      unsigned short* Cb = (unsigned short*)Cv;
#pragma unroll
      for (int i = 0; i < 4; ++i) {
        int row0 = m0 + wm + i * 16 + quad * 4;
#pragma unroll
        for (int j = 0; j < 4; ++j) {
          int col = n0 + wn + j * 16 + l15;
#pragma unroll
          for (int r = 0; r < 4; ++r)
            Cb[(size_t)(row0 + r) * N + col] = f2bf(acc[i][j][r]);
        }
      }
    } else {
      unsigned short* Vo = (unsigned short*)Cv;
#pragma unroll
      for (int i = 0; i < 4; ++i) {
        int m = m0 + wm + i * 16 + quad * 4;      // token index, 4 consecutive
        int bb = m >> 11, tt = m & 2047;
#pragma unroll
        for (int j = 0; j < 4; ++j) {
          int n = n0 + wn + j * 16 + l15;
          int hh = n >> 6, dd = n & 63;
          ushort4 pk;
          pk.x = f2bf(acc[i][j][0]); pk.y = f2bf(acc[i][j][1]);
          pk.z = f2bf(acc[i][j][2]); pk.w = f2bf(acc[i][j][3]);
          *(ushort4*)(Vo + (((size_t)bb * 16 + hh) * 64 + dd) * T_ + tt) = pk;
        }
      }
    }
  } else {
    float* Cf = (float*)Cv;
#pragma unroll
    for (int j = 0; j < 4; ++j) {
      int col = n0 + wn + j * 16 + l15;
      float bv = bias[col];
#pragma unroll
      for (int i = 0; i < 4; ++i) {
        int row0 = m0 + wm + i * 16 + quad * 4;
#pragma unroll
        for (int r = 0; r < 4; ++r)
          Cf[(size_t)(row0 + r) * N + col] = acc[i][j][r] + bv;
      }
    }
  }
}

// ---------------- flash attention (S^T/O^T formulation), causal, BC=128 ----
// Q/K in [B,T,H*D] bf16; VT in [B][H][64][T] bf16; O out [B,T,H*D] bf16.
// grid 1024: rr=id>>8, cc=id&255, g=cc>>6, bh=cc&63; t = {g,7-g,8+g,15-g}[rr]
// so each CU's 4 rounds sum to constant work; bh constant per slot (L2 reuse).
__global__ __launch_bounds__(256, 3) void flash_kernel(
    const unsigned short* __restrict__ Qh, const unsigned short* __restrict__ Kh,
    const unsigned short* __restrict__ VT, unsigned short* __restrict__ Oh)
{
  __shared__ __align__(16) short Ks[128 * 64];       // [key][c], per-row chunk-swizzled
  __shared__ __align__(16) short Vt[2][64 * 64];     // [half][d][key], chunk-swizzled
  __shared__ __align__(16) short Ps[4][32 * 72];     // per-wave P [qrow][key]

  const int tid = threadIdx.x, lane = tid & 63, wave = tid >> 6;
  const int quad = lane >> 4, l15 = lane & 15;
  const int id = blockIdx.x;
  const int rr = id >> 8, cc = id & 255, g = cc >> 6, bh = cc & 63;
  const int t = (rr == 0) ? g : (rr == 1) ? 7 - g : (rr == 2) ? 8 + g : 15 - g;
  const int b = bh >> 4, h = bh & 15;
  const int q0 = t * 128;

  const unsigned short* Qbase = Qh + (size_t)b * T_ * NDIM + h * 64;
  const unsigned short* Kbase = Kh + (size_t)b * T_ * NDIM + h * 64;
  const unsigned short* Vbase = VT + ((size_t)(b * 16 + h) * 64) * T_;   // rows d, stride T_

  const int wrow_lo = q0 + wave * 32;

  // Q fragments (B-operand rows = qrow)
  bfrag qfr[2][2];
#pragma unroll
  for (int j = 0; j < 2; ++j)
#pragma unroll
    for (int ks = 0; ks < 2; ++ks)
      qfr[j][ks] = *(const bfrag*)(Qbase + (size_t)(wrow_lo + j * 16 + l15) * NDIM + ks * 32 + quad * 8);

  float l_st[2] = {0.f, 0.f};
  f32x4 o_acc[2][4] = {};
  short* pw = &Ps[wave][0];
  const float c32 = 0.045084220f;   // log2(e)/32

  for (int kv0 = 0; kv0 < q0 + 128; kv0 += 128) {
    // stage K [128 keys][64 c] and V^T [2][64 d][64 keys], one burst, async
#pragma unroll
    for (int i = 0; i < 4; ++i) {
      int p0 = (wave * 4 + i) * 64;
      int p = p0 + lane;
      int kr = p >> 3, kcl = (p & 7) ^ (kr & 7);
      async_load16(Kbase + (size_t)(kv0 + kr) * NDIM + kcl * 8, (char*)Ks + p0 * 16);
      int hh = p >> 9, d = (p >> 3) & 63, vcl = (p & 7) ^ (d & 7);
      async_load16(Vbase + (size_t)d * T_ + kv0 + hh * 64 + vcl * 8, (char*)Vt + p0 * 16);
    }
    __syncthreads();

#pragma unroll
    for (int hf = 0; hf < 2; ++hf) {
      const int kvh = kv0 + hf * 64;
      if (kvh > wrow_lo + 31) break;

      // S^T = K * Q^T : sv[j][i], row key=i*16+quad*4+r (local), col qrow=j*16+l15
      f32x4 sv[2][4] = {};
#pragma unroll
      for (int ks = 0; ks < 2; ++ks) {
        bfrag kf[4];
#pragma unroll
        for (int i = 0; i < 4; ++i) {
          int key = i * 16 + l15;
          int c = (ks * 4 + quad) ^ (key & 7);
          kf[i] = *(const bfrag*)(Ks + (hf * 64 + key) * 64 + c * 8);
        }
#pragma unroll
        for (int j = 0; j < 2; ++j)
#pragma unroll
          for (int i = 0; i < 4; ++i)
            sv[j][i] = __builtin_amdgcn_mfma_f32_16x16x32_bf16(kf[i], qfr[j][ks], sv[j][i], 0, 0, 0);
      }

      // p = exp2(S_raw * log2e/32); causal zeroing on diagonal tiles only
#pragma unroll
      for (int j = 0; j < 2; ++j)
#pragma unroll
        for (int i = 0; i < 4; ++i)
#pragma unroll
          for (int r = 0; r < 4; ++r)
            sv[j][i][r] = __builtin_amdgcn_exp2f(sv[j][i][r] * c32);
      if (kvh + 63 > wrow_lo) {
#pragma unroll
        for (int j = 0; j < 2; ++j) {
          int qr = wrow_lo + j * 16 + l15;
#pragma unroll
          for (int i = 0; i < 4; ++i) {
            int keyb = kvh + i * 16 + quad * 4;
#pragma unroll
            for (int r = 0; r < 4; ++r)
              if (keyb + r > qr) sv[j][i][r] = 0.f;
          }
        }
      }

      // l partials (keys in-lane) + packed P store
#pragma unroll
      for (int j = 0; j < 2; ++j) {
#pragma unroll
        for (int i = 0; i < 4; ++i) {
          l_st[j] += sv[j][i][0] + sv[j][i][1] + sv[j][i][2] + sv[j][i][3];
          uint2 pk;
          pk.x = pack_bf2(sv[j][i][0], sv[j][i][1]);
          pk.y = pack_bf2(sv[j][i][2], sv[j][i][3]);
          *(uint2*)(pw + (j * 16 + l15) * 72 + i * 16 + quad * 4) = pk;
        }
      }

      // O^T += V^T * P^T
#pragma unroll
      for (int ks = 0; ks < 2; ++ks) {
        bfrag vf[4], pf[2];
#pragma unroll
        for (int i2 = 0; i2 < 4; ++i2) {
          int d = i2 * 16 + l15;
          int c = (ks * 4 + quad) ^ (d & 7);
          vf[i2] = *(const bfrag*)(&Vt[hf][0] + d * 64 + c * 8);
        }
#pragma unroll
        for (int j = 0; j < 2; ++j)
          pf[j] = *(const bfrag*)(pw + (j * 16 + l15) * 72 + ks * 32 + quad * 8);
#pragma unroll
        for (int j = 0; j < 2; ++j)
#pragma unroll
          for (int i2 = 0; i2 < 4; ++i2)
            o_acc[j][i2] = __builtin_amdgcn_mfma_f32_16x16x32_bf16(vf[i2], pf[j], o_acc[j][i2], 0, 0, 0);
      }
    }
    __syncthreads();
  }

  // epilogue: reduce l over quad groups, scale, write packed b64
#pragma unroll
  for (int j = 0; j < 2; ++j) {
    float s = l_st[j];
    s += __shfl_xor(s, 16, 64);
    s += __shfl_xor(s, 32, 64);
    float inv = 1.f / s;
    int qr = q0 + wave * 32 + j * 16 + l15;
    size_t base = ((size_t)b * T_ + qr) * NDIM + h * 64;
#pragma unroll
    for (int i2 = 0; i2 < 4; ++i2) {
      ushort4 pk;
      pk.x = f2bf(o_acc[j][i2][0] * inv);
      pk.y = f2bf(o_acc[j][i2][1] * inv);
      pk.z = f2bf(o_acc[j][i2][2] * inv);
      pk.w = f2bf(o_acc[j][i2][3] * inv);
      *(ushort4*)(Oh + base + i2 * 16 + quad * 4) = pk;
    }
  }
}

extern "C" void kernel_launch(void* const* d_in, const int* in_sizes, int n_in,
                              void* d_out, int out_size, void* d_ws, size_t ws_size,
                              hipStream_t stream)
{
  const float* q  = (const float*)d_in[0];
  const float* k  = (const float*)d_in[1];
  const float* v  = (const float*)d_in[2];
  const float* Wq = (const float*)d_in[3];
  const float* Wk = (const float*)d_in[4];
  const float* Wv = (const float*)d_in[5];
  const float* Wo = (const float*)d_in[6];
  const float* bo = (const float*)d_in[7];
  float* out = (float*)d_out;

  char* w = (char*)d_ws;
  const size_t szBTC = (size_t)MROWS * C_ * 2;   // 16 MB
  const size_t szW   = (size_t)NDIM * C_ * 2;    // 2 MB
  unsigned short* qb   = (unsigned short*)(w);
  unsigned short* kb   = (unsigned short*)(w + szBTC);
  unsigned short* vb   = (unsigned short*)(w + 2 * szBTC);
  unsigned short* wqT  = (unsigned short*)(w + 3 * szBTC);
  unsigned short* wkT  = (unsigned short*)(w + 3 * szBTC + szW);
  unsigned short* wvT  = (unsigned short*)(w + 3 * szBTC + 2 * szW);
  unsigned short* woT  = (unsigned short*)(w + 3 * szBTC + 3 * szW);
  unsigned short* qhp  = (unsigned short*)(w + 3 * szBTC + 4 * szW);
  unsigned short* khp  = (unsigned short*)(w + 4 * szBTC + 4 * szW);
  unsigned short* vT   = (unsigned short*)(w + 5 * szBTC + 4 * szW);  // [B][H][64][T]
  unsigned short* attO = (unsigned short*)(w + 6 * szBTC + 4 * szW);

  prep_kernel<<<dim3(25600), 256, 0, stream>>>(q, k, v, qb, kb, vb,
                                               Wq, Wk, Wv, wqT, wkT, wvT, Wo, woT);

  // Q,K,V projections: 256x256-tile 8-phase GEMM (z==2 writes V transposed)
  gemm_qkv_256<<<dim3(384), 512, 0, stream>>>(
      qb, kb, vb, wqT, wkT, wvT, qhp, khp, vT);

  flash_kernel<<<dim3(1024), 256, 0, stream>>>(qhp, khp, vT, attO);

  gemm_bt_kernel<1><<<dim3(512), 256, 0, stream>>>(
      attO, attO, attO, woT, woT, woT, out, out, out, bo, MROWS, C_, NDIM);
}

// Round 3
// 307.814 us; speedup vs baseline: 1.0018x; 1.0018x over previous
//
#include <hip/hip_runtime.h>
#include <hip/hip_bf16.h>
#include <cstdint>
#include <cstddef>

#define B_  4
#define T_  2048
#define C_  1024
#define H_  16
#define D_  64
#define MROWS (B_*T_)      // 8192
#define NDIM  (H_*D_)      // 1024

typedef float  f32x4 __attribute__((ext_vector_type(4)));
typedef __bf16 bfrag __attribute__((ext_vector_type(8)));

__device__ __forceinline__ unsigned short f2bf(float f) {
  union { float f; unsigned u; } v; v.f = f;
  unsigned r = v.u + 0x7fffu + ((v.u >> 16) & 1u);
  return (unsigned short)(r >> 16);
}

__device__ __forceinline__ void async_load16(const void* g, void* l) {
  __builtin_amdgcn_global_load_lds((__attribute__((address_space(1))) void*)(void*)g,
                                   (__attribute__((address_space(3))) void*)l,
                                   16, 0, 0);
}

// pack two f32 -> two bf16 (round-half-up) in one u32
__device__ __forceinline__ unsigned pack_bf2(float f0, float f1) {
  unsigned a0 = __float_as_uint(f0) + 0x8000u;
  unsigned a1 = __float_as_uint(f1) + 0x8000u;
  return __builtin_amdgcn_perm(a1, a0, 0x07060302u);
}

// ---------------- fused prep: cvt q/k/v -> bf16, transpose Wq/Wk/Wv, Wo ----
// blocks [0,24576): cvt.  [24576,25344): wqkv transpose.  [25344,25600): wo.
__global__ __launch_bounds__(256) void prep_kernel(
    const float* __restrict__ q, const float* __restrict__ k, const float* __restrict__ v,
    unsigned short* __restrict__ qb, unsigned short* __restrict__ kb, unsigned short* __restrict__ vb,
    const float* __restrict__ Wq, const float* __restrict__ Wk, const float* __restrict__ Wv,
    unsigned short* __restrict__ wqT, unsigned short* __restrict__ wkT, unsigned short* __restrict__ wvT,
    const float* __restrict__ Wo, unsigned short* __restrict__ woT)
{
  const int id = blockIdx.x, tid = threadIdx.x;
  if (id < 24576) {
    int z = id >> 13, blk = id & 8191;
    const float* in = z == 0 ? q : z == 1 ? k : v;
    unsigned short* out = z == 0 ? qb : z == 1 ? kb : vb;
    int i = (blk * 256 + tid) * 4;
    float4 vv = *(const float4*)(in + i);
    ushort4 r;
    r.x = f2bf(vv.x); r.y = f2bf(vv.y); r.z = f2bf(vv.z); r.w = f2bf(vv.w);
    *(ushort4*)(out + i) = r;
  } else if (id < 25344) {
    int u = id - 24576;
    int z = u >> 4, cblk = u & 15;
    int sel = z >> 4, h = z & 15;
    const float* in = (sel == 0 ? Wq : sel == 1 ? Wk : Wv) + (size_t)h * C_ * D_; // [C][D]
    unsigned short* out = (sel == 0 ? wqT : sel == 1 ? wkT : wvT) + (size_t)h * D_ * C_; // [D][C]
    __shared__ float tile[64][65];
    int c0 = cblk * 64;
    int x = tid & 63, y4 = tid >> 6;
    for (int r = y4; r < 64; r += 4)
      tile[r][x] = in[(size_t)(c0 + r) * D_ + x];
    __syncthreads();
    for (int r = y4; r < 64; r += 4)
      out[(size_t)r * C_ + c0 + x] = f2bf(tile[x][r]);
  } else {
    int u = id - 25344;
    __shared__ float tile[64][65];
    int i0 = (u >> 4) * 64, j0 = (u & 15) * 64;
    int x = tid & 63, y4 = tid >> 6;
    for (int r = y4; r < 64; r += 4)
      tile[r][x] = Wo[(size_t)(i0 + r) * C_ + j0 + x];
    __syncthreads();
    for (int r = y4; r < 64; r += 4)
      woT[(size_t)(j0 + r) * NDIM + i0 + x] = f2bf(tile[x][r]);
  }
}

// ---------------- GEMM: C[M,N] = A[M,K] * Bt[N,K]^T  (bf16 in, fp32 acc) ----
// 256x128 tile, BK=64, 512 threads (8 waves, 4Mx2N of 64x64), 48 KiB LDS ->
// 3 blocks/CU (implicit inter-block pipeline hides the sync drain, m114).
// 2-phase K-loop (proven round-0 structure).  Grids are EXACT multiples of
// 256 CUs: EPI0 (qkv) 32mb x 8nb x 3z = 768 = 3 rounds; EPI1 32x8 = 256 = 1.
// XCD swizzle: xcd = id&7 owns a 4-mb band; nb iterates fastest (A L2 reuse).
// EPI 0: z<2 -> bf16 row-major out; z==2 -> V-transposed bf16 out
//   element (m=b*2048+t, n=h*64+d) -> out[((b*16+h)*64+d)*T_ + t].
// EPI 1: fp32 out + bias.
template <int EPI>
__global__ __launch_bounds__(512, 4) void gemm_bt2(
    const unsigned short* __restrict__ A0, const unsigned short* __restrict__ A1, const unsigned short* __restrict__ A2,
    const unsigned short* __restrict__ B0, const unsigned short* __restrict__ B1, const unsigned short* __restrict__ B2,
    void* C0, void* C1, void* C2, const float* __restrict__ bias)
{
  constexpr int K = C_;     // 1024
  constexpr int N = NDIM;   // 1024
  __shared__ __align__(16) short As[256 * 64];   // 32 KiB
  __shared__ __align__(16) short Bs[128 * 64];   // 16 KiB

  const int id = blockIdx.x;
  const int xcd = id & 7, s = id >> 3;
  const int z = s >> 5;            // EPI0: s in [0,96) -> z in {0,1,2}; EPI1: s in [0,32) -> 0
  const int t = s & 31;
  const int mb = xcd * 4 + (t >> 3);   // 32 m-blocks of 256 rows
  const int nb = t & 7;                // 8 n-blocks of 128 cols

  const unsigned short* A  = z == 0 ? A0 : z == 1 ? A1 : A2;
  const unsigned short* Bt = z == 0 ? B0 : z == 1 ? B1 : B2;
  void* Cv                 = z == 0 ? C0 : z == 1 ? C1 : C2;

  const int tid = threadIdx.x, lane = tid & 63, wave = tid >> 6;
  const int quad = lane >> 4, l15 = lane & 15;
  const int m0 = mb * 256, n0 = nb * 128;
  const int wm = (wave >> 1) * 64, wn = (wave & 1) * 64;
  const int wbase = tid & ~63;         // wave-uniform LDS chunk base

  f32x4 acc[4][4] = {};

  for (int k0 = 0; k0 < K; k0 += 64) {
    // stage A 256x64 (4 chunks/thread) + B 128x64 (2 chunks/thread),
    // linear LDS dest + chunk-XOR pre-swizzled global source.
#pragma unroll
    for (int i = 0; i < 4; ++i) {
      int p0 = i * 512 + wbase;
      int p = p0 + lane;
      int m = p >> 3, cl = (p & 7) ^ (m & 7);
      async_load16(A + (size_t)(m0 + m) * K + k0 + cl * 8, (char*)As + p0 * 16);
    }
#pragma unroll
    for (int i = 0; i < 2; ++i) {
      int p0 = i * 512 + wbase;
      int p = p0 + lane;
      int m = p >> 3, cl = (p & 7) ^ (m & 7);
      async_load16(Bt + (size_t)(n0 + m) * K + k0 + cl * 8, (char*)Bs + p0 * 16);
    }
    __syncthreads();
#pragma unroll
    for (int ks = 0; ks < 2; ++ks) {
      bfrag af[4], bf[4];
#pragma unroll
      for (int i = 0; i < 4; ++i) {
        int m = wm + i * 16 + l15;
        int c = (ks * 4 + quad) ^ (m & 7);
        af[i] = *(const bfrag*)(As + m * 64 + c * 8);
        int n = wn + i * 16 + l15;
        int c2 = (ks * 4 + quad) ^ (n & 7);
        bf[i] = *(const bfrag*)(Bs + n * 64 + c2 * 8);
      }
#pragma unroll
      for (int i = 0; i < 4; ++i)
#pragma unroll
        for (int j = 0; j < 4; ++j)
          acc[i][j] = __builtin_amdgcn_mfma_f32_16x16x32_bf16(af[i], bf[j], acc[i][j], 0, 0, 0);
    }
    __syncthreads();
  }

  if constexpr (EPI == 0) {
    if (z < 2) {
      unsigned short* Cb = (unsigned short*)Cv;
#pragma unroll
      for (int i = 0; i < 4; ++i) {
        int row0 = m0 + wm + i * 16 + quad * 4;
#pragma unroll
        for (int j = 0; j < 4; ++j) {
          int col = n0 + wn + j * 16 + l15;
#pragma unroll
          for (int r = 0; r < 4; ++r)
            Cb[(size_t)(row0 + r) * N + col] = f2bf(acc[i][j][r]);
        }
      }
    } else {
      unsigned short* Vo = (unsigned short*)Cv;
#pragma unroll
      for (int i = 0; i < 4; ++i) {
        int m = m0 + wm + i * 16 + quad * 4;      // token index, 4 consecutive
        int bb = m >> 11, tt = m & 2047;
#pragma unroll
        for (int j = 0; j < 4; ++j) {
          int n = n0 + wn + j * 16 + l15;
          int hh = n >> 6, dd = n & 63;
          ushort4 pk;
          pk.x = f2bf(acc[i][j][0]); pk.y = f2bf(acc[i][j][1]);
          pk.z = f2bf(acc[i][j][2]); pk.w = f2bf(acc[i][j][3]);
          *(ushort4*)(Vo + (((size_t)bb * 16 + hh) * 64 + dd) * T_ + tt) = pk;
        }
      }
    }
  } else {
    float* Cf = (float*)Cv;
#pragma unroll
    for (int j = 0; j < 4; ++j) {
      int col = n0 + wn + j * 16 + l15;
      float bv = bias[col];
#pragma unroll
      for (int i = 0; i < 4; ++i) {
        int row0 = m0 + wm + i * 16 + quad * 4;
#pragma unroll
        for (int r = 0; r < 4; ++r)
          Cf[(size_t)(row0 + r) * N + col] = acc[i][j][r] + bv;
      }
    }
  }
}

// ---------------- flash attention (S^T/O^T formulation), causal, BC=128 ----
// Q/K in [B,T,H*D] bf16; VT in [B][H][64][T] bf16; O out [B,T,H*D] bf16.
// grid 1024: rr=id>>8, cc=id&255, g=cc>>6, bh=cc&63; t = {g,7-g,8+g,15-g}[rr]
// so each CU's 4 rounds sum to constant work; bh constant per slot (L2 reuse).
__global__ __launch_bounds__(256, 3) void flash_kernel(
    const unsigned short* __restrict__ Qh, const unsigned short* __restrict__ Kh,
    const unsigned short* __restrict__ VT, unsigned short* __restrict__ Oh)
{
  __shared__ __align__(16) short Ks[128 * 64];       // [key][c], per-row chunk-swizzled
  __shared__ __align__(16) short Vt[2][64 * 64];     // [half][d][key], chunk-swizzled
  __shared__ __align__(16) short Ps[4][32 * 72];     // per-wave P [qrow][key]

  const int tid = threadIdx.x, lane = tid & 63, wave = tid >> 6;
  const int quad = lane >> 4, l15 = lane & 15;
  const int id = blockIdx.x;
  const int rr = id >> 8, cc = id & 255, g = cc >> 6, bh = cc & 63;
  const int t = (rr == 0) ? g : (rr == 1) ? 7 - g : (rr == 2) ? 8 + g : 15 - g;
  const int b = bh >> 4, h = bh & 15;
  const int q0 = t * 128;

  const unsigned short* Qbase = Qh + (size_t)b * T_ * NDIM + h * 64;
  const unsigned short* Kbase = Kh + (size_t)b * T_ * NDIM + h * 64;
  const unsigned short* Vbase = VT + ((size_t)(b * 16 + h) * 64) * T_;   // rows d, stride T_

  const int wrow_lo = q0 + wave * 32;

  // Q fragments (B-operand rows = qrow)
  bfrag qfr[2][2];
#pragma unroll
  for (int j = 0; j < 2; ++j)
#pragma unroll
    for (int ks = 0; ks < 2; ++ks)
      qfr[j][ks] = *(const bfrag*)(Qbase + (size_t)(wrow_lo + j * 16 + l15) * NDIM + ks * 32 + quad * 8);

  float l_st[2] = {0.f, 0.f};
  f32x4 o_acc[2][4] = {};
  short* pw = &Ps[wave][0];
  const float c32 = 0.045084220f;   // log2(e)/32

  for (int kv0 = 0; kv0 < q0 + 128; kv0 += 128) {
    // stage K [128 keys][64 c] and V^T [2][64 d][64 keys], one burst, async
#pragma unroll
    for (int i = 0; i < 4; ++i) {
      int p0 = (wave * 4 + i) * 64;
      int p = p0 + lane;
      int kr = p >> 3, kcl = (p & 7) ^ (kr & 7);
      async_load16(Kbase + (size_t)(kv0 + kr) * NDIM + kcl * 8, (char*)Ks + p0 * 16);
      int hh = p >> 9, d = (p >> 3) & 63, vcl = (p & 7) ^ (d & 7);
      async_load16(Vbase + (size_t)d * T_ + kv0 + hh * 64 + vcl * 8, (char*)Vt + p0 * 16);
    }
    __syncthreads();

#pragma unroll
    for (int hf = 0; hf < 2; ++hf) {
      const int kvh = kv0 + hf * 64;
      if (kvh > wrow_lo + 31) break;

      // S^T = K * Q^T : sv[j][i], row key=i*16+quad*4+r (local), col qrow=j*16+l15
      f32x4 sv[2][4] = {};
#pragma unroll
      for (int ks = 0; ks < 2; ++ks) {
        bfrag kf[4];
#pragma unroll
        for (int i = 0; i < 4; ++i) {
          int key = i * 16 + l15;
          int c = (ks * 4 + quad) ^ (key & 7);
          kf[i] = *(const bfrag*)(Ks + (hf * 64 + key) * 64 + c * 8);
        }
#pragma unroll
        for (int j = 0; j < 2; ++j)
#pragma unroll
          for (int i = 0; i < 4; ++i)
            sv[j][i] = __builtin_amdgcn_mfma_f32_16x16x32_bf16(kf[i], qfr[j][ks], sv[j][i], 0, 0, 0);
      }

      // p = exp2(S_raw * log2e/32); causal zeroing on diagonal tiles only
#pragma unroll
      for (int j = 0; j < 2; ++j)
#pragma unroll
        for (int i = 0; i < 4; ++i)
#pragma unroll
          for (int r = 0; r < 4; ++r)
            sv[j][i][r] = __builtin_amdgcn_exp2f(sv[j][i][r] * c32);
      if (kvh + 63 > wrow_lo) {
#pragma unroll
        for (int j = 0; j < 2; ++j) {
          int qr = wrow_lo + j * 16 + l15;
#pragma unroll
          for (int i = 0; i < 4; ++i) {
            int keyb = kvh + i * 16 + quad * 4;
#pragma unroll
            for (int r = 0; r < 4; ++r)
              if (keyb + r > qr) sv[j][i][r] = 0.f;
          }
        }
      }

      // l partials (keys in-lane) + packed P store
#pragma unroll
      for (int j = 0; j < 2; ++j) {
#pragma unroll
        for (int i = 0; i < 4; ++i) {
          l_st[j] += sv[j][i][0] + sv[j][i][1] + sv[j][i][2] + sv[j][i][3];
          uint2 pk;
          pk.x = pack_bf2(sv[j][i][0], sv[j][i][1]);
          pk.y = pack_bf2(sv[j][i][2], sv[j][i][3]);
          *(uint2*)(pw + (j * 16 + l15) * 72 + i * 16 + quad * 4) = pk;
        }
      }

      // O^T += V^T * P^T
#pragma unroll
      for (int ks = 0; ks < 2; ++ks) {
        bfrag vf[4], pf[2];
#pragma unroll
        for (int i2 = 0; i2 < 4; ++i2) {
          int d = i2 * 16 + l15;
          int c = (ks * 4 + quad) ^ (d & 7);
          vf[i2] = *(const bfrag*)(&Vt[hf][0] + d * 64 + c * 8);
        }
#pragma unroll
        for (int j = 0; j < 2; ++j)
          pf[j] = *(const bfrag*)(pw + (j * 16 + l15) * 72 + ks * 32 + quad * 8);
#pragma unroll
        for (int j = 0; j < 2; ++j)
#pragma unroll
          for (int i2 = 0; i2 < 4; ++i2)
            o_acc[j][i2] = __builtin_amdgcn_mfma_f32_16x16x32_bf16(vf[i2], pf[j], o_acc[j][i2], 0, 0, 0);
      }
    }
    __syncthreads();
  }

  // epilogue: reduce l over quad groups, scale, write packed b64
#pragma unroll
  for (int j = 0; j < 2; ++j) {
    float s = l_st[j];
    s += __shfl_xor(s, 16, 64);
    s += __shfl_xor(s, 32, 64);
    float inv = 1.f / s;
    int qr = q0 + wave * 32 + j * 16 + l15;
    size_t base = ((size_t)b * T_ + qr) * NDIM + h * 64;
#pragma unroll
    for (int i2 = 0; i2 < 4; ++i2) {
      ushort4 pk;
      pk.x = f2bf(o_acc[j][i2][0] * inv);
      pk.y = f2bf(o_acc[j][i2][1] * inv);
      pk.z = f2bf(o_acc[j][i2][2] * inv);
      pk.w = f2bf(o_acc[j][i2][3] * inv);
      *(ushort4*)(Oh + base + i2 * 16 + quad * 4) = pk;
    }
  }
}

extern "C" void kernel_launch(void* const* d_in, const int* in_sizes, int n_in,
                              void* d_out, int out_size, void* d_ws, size_t ws_size,
                              hipStream_t stream)
{
  const float* q  = (const float*)d_in[0];
  const float* k  = (const float*)d_in[1];
  const float* v  = (const float*)d_in[2];
  const float* Wq = (const float*)d_in[3];
  const float* Wk = (const float*)d_in[4];
  const float* Wv = (const float*)d_in[5];
  const float* Wo = (const float*)d_in[6];
  const float* bo = (const float*)d_in[7];
  float* out = (float*)d_out;

  char* w = (char*)d_ws;
  const size_t szBTC = (size_t)MROWS * C_ * 2;   // 16 MB
  const size_t szW   = (size_t)NDIM * C_ * 2;    // 2 MB
  unsigned short* qb   = (unsigned short*)(w);
  unsigned short* kb   = (unsigned short*)(w + szBTC);
  unsigned short* vb   = (unsigned short*)(w + 2 * szBTC);
  unsigned short* wqT  = (unsigned short*)(w + 3 * szBTC);
  unsigned short* wkT  = (unsigned short*)(w + 3 * szBTC + szW);
  unsigned short* wvT  = (unsigned short*)(w + 3 * szBTC + 2 * szW);
  unsigned short* woT  = (unsigned short*)(w + 3 * szBTC + 3 * szW);
  unsigned short* qhp  = (unsigned short*)(w + 3 * szBTC + 4 * szW);
  unsigned short* khp  = (unsigned short*)(w + 4 * szBTC + 4 * szW);
  unsigned short* vT   = (unsigned short*)(w + 5 * szBTC + 4 * szW);  // [B][H][64][T]
  unsigned short* attO = (unsigned short*)(w + 6 * szBTC + 4 * szW);

  prep_kernel<<<dim3(25600), 256, 0, stream>>>(q, k, v, qb, kb, vb,
                                               Wq, Wk, Wv, wqT, wkT, wvT, Wo, woT);

  // Q,K,V projections: 256x128-tile 2-phase GEMM, 768 blocks = 3 exact rounds
  gemm_bt2<0><<<dim3(768), 512, 0, stream>>>(
      qb, kb, vb, wqT, wkT, wvT, qhp, khp, vT, nullptr);

  flash_kernel<<<dim3(1024), 256, 0, stream>>>(qhp, khp, vT, attO);

  // output projection: 256 blocks = 1 exact round
  gemm_bt2<1><<<dim3(256), 512, 0, stream>>>(
      attO, attO, attO, woT, woT, woT, out, out, out, bo);
}

// Round 5
// 295.557 us; speedup vs baseline: 1.0434x; 1.0415x over previous
//
#include <hip/hip_runtime.h>
#include <hip/hip_bf16.h>
#include <cstdint>
#include <cstddef>

#define B_  4
#define T_  2048
#define C_  1024
#define H_  16
#define D_  64
#define MROWS (B_*T_)      // 8192
#define NDIM  (H_*D_)      // 1024

typedef float  f32x4 __attribute__((ext_vector_type(4)));
typedef __bf16 bfrag __attribute__((ext_vector_type(8)));

__device__ __forceinline__ unsigned short f2bf(float f) {
  union { float f; unsigned u; } v; v.f = f;
  unsigned r = v.u + 0x7fffu + ((v.u >> 16) & 1u);
  return (unsigned short)(r >> 16);
}

__device__ __forceinline__ void async_load16(const void* g, void* l) {
  __builtin_amdgcn_global_load_lds((__attribute__((address_space(1))) void*)(void*)g,
                                   (__attribute__((address_space(3))) void*)l,
                                   16, 0, 0);
}

// pack two f32 -> 2xbf16 (RNE) in one VALU op; low16 = cvt(f0)
__device__ __forceinline__ unsigned cvt_pk_bf16(float f0, float f1) {
  unsigned r;
  asm("v_cvt_pk_bf16_f32 %0, %1, %2" : "=v"(r) : "v"(f0), "v"(f1));
  return r;
}

// ---------------- fused prep: cvt q/k/v -> bf16, transpose Wq/Wk/Wv, Wo ----
// blocks [0,24576): cvt.  [24576,25344): wqkv transpose.  [25344,25600): wo.
__global__ __launch_bounds__(256) void prep_kernel(
    const float* __restrict__ q, const float* __restrict__ k, const float* __restrict__ v,
    unsigned short* __restrict__ qb, unsigned short* __restrict__ kb, unsigned short* __restrict__ vb,
    const float* __restrict__ Wq, const float* __restrict__ Wk, const float* __restrict__ Wv,
    unsigned short* __restrict__ wqT, unsigned short* __restrict__ wkT, unsigned short* __restrict__ wvT,
    const float* __restrict__ Wo, unsigned short* __restrict__ woT)
{
  const int id = blockIdx.x, tid = threadIdx.x;
  if (id < 24576) {
    int z = id >> 13, blk = id & 8191;
    const float* in = z == 0 ? q : z == 1 ? k : v;
    unsigned short* out = z == 0 ? qb : z == 1 ? kb : vb;
    int i = (blk * 256 + tid) * 4;
    float4 vv = *(const float4*)(in + i);
    ushort4 r;
    r.x = f2bf(vv.x); r.y = f2bf(vv.y); r.z = f2bf(vv.z); r.w = f2bf(vv.w);
    *(ushort4*)(out + i) = r;
  } else if (id < 25344) {
    int u = id - 24576;
    int z = u >> 4, cblk = u & 15;
    int sel = z >> 4, h = z & 15;
    const float* in = (sel == 0 ? Wq : sel == 1 ? Wk : Wv) + (size_t)h * C_ * D_; // [C][D]
    unsigned short* out = (sel == 0 ? wqT : sel == 1 ? wkT : wvT) + (size_t)h * D_ * C_; // [D][C]
    __shared__ float tile[64][65];
    int c0 = cblk * 64;
    int x = tid & 63, y4 = tid >> 6;
    for (int r = y4; r < 64; r += 4)
      tile[r][x] = in[(size_t)(c0 + r) * D_ + x];
    __syncthreads();
    for (int r = y4; r < 64; r += 4)
      out[(size_t)r * C_ + c0 + x] = f2bf(tile[x][r]);
  } else {
    int u = id - 25344;
    __shared__ float tile[64][65];
    int i0 = (u >> 4) * 64, j0 = (u & 15) * 64;
    int x = tid & 63, y4 = tid >> 6;
    for (int r = y4; r < 64; r += 4)
      tile[r][x] = Wo[(size_t)(i0 + r) * C_ + j0 + x];
    __syncthreads();
    for (int r = y4; r < 64; r += 4)
      woT[(size_t)(j0 + r) * NDIM + i0 + x] = f2bf(tile[x][r]);
  }
}

// ---------------- GEMM: C[M,N] = A[M,K] * Bt[N,K]^T  (bf16 in, fp32 acc) ----
// R3-proven geometry: 256x128 tile, BK=64, 512 threads (8 waves, 4Mx2N of
// 64x64), 48 KiB LDS, VGPR~84 -> 2 blocks/CU; 2-phase K-loop.
// Grids: EPI0 (qkv) 32mb x 8nb x 3z = 768; EPI1 32x8 = 256 = 1 exact round.
// XCD swizzle: xcd = id&7 owns a 4-mb band; nb iterates fastest (A L2 reuse).
// EPI 0: z==0 -> bf16 out PRE-SCALED by log2(e)/32 (flash softmax folds it);
//        z==1 -> bf16 row-major; z==2 -> V-transposed bf16 out
//   element (m=b*2048+t, n=h*64+d) -> out[((b*16+h)*64+d)*T_ + t].
// EPI 1: fp32 out + bias.
template <int EPI>
__global__ __launch_bounds__(512, 4) void gemm_bt2(
    const unsigned short* __restrict__ A0, const unsigned short* __restrict__ A1, const unsigned short* __restrict__ A2,
    const unsigned short* __restrict__ B0, const unsigned short* __restrict__ B1, const unsigned short* __restrict__ B2,
    void* C0, void* C1, void* C2, const float* __restrict__ bias)
{
  constexpr int K = C_;     // 1024
  constexpr int N = NDIM;   // 1024
  __shared__ __align__(16) short As[256 * 64];   // 32 KiB
  __shared__ __align__(16) short Bs[128 * 64];   // 16 KiB

  const int id = blockIdx.x;
  const int xcd = id & 7, s = id >> 3;
  const int z = s >> 5;            // EPI0: s in [0,96) -> z in {0,1,2}; EPI1: 0
  const int t = s & 31;
  const int mb = xcd * 4 + (t >> 3);   // 32 m-blocks of 256 rows
  const int nb = t & 7;                // 8 n-blocks of 128 cols

  const unsigned short* A  = z == 0 ? A0 : z == 1 ? A1 : A2;
  const unsigned short* Bt = z == 0 ? B0 : z == 1 ? B1 : B2;
  void* Cv                 = z == 0 ? C0 : z == 1 ? C1 : C2;

  const int tid = threadIdx.x, lane = tid & 63, wave = tid >> 6;
  const int quad = lane >> 4, l15 = lane & 15;
  const int m0 = mb * 256, n0 = nb * 128;
  const int wm = (wave >> 1) * 64, wn = (wave & 1) * 64;
  const int wbase = tid & ~63;         // wave-uniform LDS chunk base

  f32x4 acc[4][4] = {};

  for (int k0 = 0; k0 < K; k0 += 64) {
    // stage A 256x64 (4 chunks/thread x 512 thr = 32 KiB) + B 128x64
    // (2 chunks/thread = 16 KiB); linear LDS dest + chunk-XOR global source.
#pragma unroll
    for (int i = 0; i < 4; ++i) {
      int p0 = i * 512 + wbase;
      int p = p0 + lane;
      int m = p >> 3, cl = (p & 7) ^ (m & 7);
      async_load16(A + (size_t)(m0 + m) * K + k0 + cl * 8, (char*)As + p0 * 16);
    }
#pragma unroll
    for (int i = 0; i < 2; ++i) {
      int p0 = i * 512 + wbase;
      int p = p0 + lane;
      int m = p >> 3, cl = (p & 7) ^ (m & 7);
      async_load16(Bt + (size_t)(n0 + m) * K + k0 + cl * 8, (char*)Bs + p0 * 16);
    }
    __syncthreads();
#pragma unroll
    for (int ks = 0; ks < 2; ++ks) {
      bfrag af[4], bf[4];
#pragma unroll
      for (int i = 0; i < 4; ++i) {
        int m = wm + i * 16 + l15;
        int c = (ks * 4 + quad) ^ (m & 7);
        af[i] = *(const bfrag*)(As + m * 64 + c * 8);
        int n = wn + i * 16 + l15;
        int c2 = (ks * 4 + quad) ^ (n & 7);
        bf[i] = *(const bfrag*)(Bs + n * 64 + c2 * 8);
      }
#pragma unroll
      for (int i = 0; i < 4; ++i)
#pragma unroll
        for (int j = 0; j < 4; ++j)
          acc[i][j] = __builtin_amdgcn_mfma_f32_16x16x32_bf16(af[i], bf[j], acc[i][j], 0, 0, 0);
    }
    __syncthreads();
  }

  if constexpr (EPI == 0) {
    if (z < 2) {
      // z==0 (Q): fold softmax scale log2(e)/32 into the stored Q
      const float sc = (z == 0) ? 0.045084220f : 1.0f;
      unsigned short* Cb = (unsigned short*)Cv;
#pragma unroll
      for (int i = 0; i < 4; ++i) {
        int row0 = m0 + wm + i * 16 + quad * 4;
#pragma unroll
        for (int j = 0; j < 4; ++j) {
          int col = n0 + wn + j * 16 + l15;
#pragma unroll
          for (int r = 0; r < 4; ++r)
            Cb[(size_t)(row0 + r) * N + col] = f2bf(acc[i][j][r] * sc);
        }
      }
    } else {
      unsigned short* Vo = (unsigned short*)Cv;
#pragma unroll
      for (int i = 0; i < 4; ++i) {
        int m = m0 + wm + i * 16 + quad * 4;      // token index, 4 consecutive
        int bb = m >> 11, tt = m & 2047;
#pragma unroll
        for (int j = 0; j < 4; ++j) {
          int n = n0 + wn + j * 16 + l15;
          int hh = n >> 6, dd = n & 63;
          ushort4 pk;
          pk.x = f2bf(acc[i][j][0]); pk.y = f2bf(acc[i][j][1]);
          pk.z = f2bf(acc[i][j][2]); pk.w = f2bf(acc[i][j][3]);
          *(ushort4*)(Vo + (((size_t)bb * 16 + hh) * 64 + dd) * T_ + tt) = pk;
        }
      }
    }
  } else {
    float* Cf = (float*)Cv;
#pragma unroll
    for (int j = 0; j < 4; ++j) {
      int col = n0 + wn + j * 16 + l15;
      float bv = bias[col];
#pragma unroll
      for (int i = 0; i < 4; ++i) {
        int row0 = m0 + wm + i * 16 + quad * 4;
#pragma unroll
        for (int r = 0; r < 4; ++r)
          Cf[(size_t)(row0 + r) * N + col] = acc[i][j][r] + bv;
      }
    }
  }
}

// ---------------- flash attention (S^T/O^T formulation), causal, BC=128 ----
// Q/K in [B,T,H*D] bf16 (Q pre-scaled by log2e/32); VT in [B][H][64][T] bf16;
// O out [B,T,H*D] bf16.
// grid 1024: rr=id>>8, cc=id&255, g=cc>>6, bh=cc&63; t = {g,7-g,8+g,15-g}[rr]
// so each CU's 4 rounds sum to constant work; bh constant per slot (L2 reuse).
__global__ __launch_bounds__(256, 3) void flash_kernel(
    const unsigned short* __restrict__ Qh, const unsigned short* __restrict__ Kh,
    const unsigned short* __restrict__ VT, unsigned short* __restrict__ Oh)
{
  __shared__ __align__(16) short Ks[128 * 64];       // [key][c], per-row chunk-swizzled
  __shared__ __align__(16) short Vt[2][64 * 64];     // [half][d][key], chunk-swizzled
  __shared__ __align__(16) short Ps[4][32 * 72];     // per-wave P [qrow][key]

  const int tid = threadIdx.x, lane = tid & 63, wave = tid >> 6;
  const int quad = lane >> 4, l15 = lane & 15;
  const int id = blockIdx.x;
  const int rr = id >> 8, cc = id & 255, g = cc >> 6, bh = cc & 63;
  const int t = (rr == 0) ? g : (rr == 1) ? 7 - g : (rr == 2) ? 8 + g : 15 - g;
  const int b = bh >> 4, h = bh & 15;
  const int q0 = t * 128;

  const unsigned short* Qbase = Qh + (size_t)b * T_ * NDIM + h * 64;
  const unsigned short* Kbase = Kh + (size_t)b * T_ * NDIM + h * 64;
  const unsigned short* Vbase = VT + ((size_t)(b * 16 + h) * 64) * T_;   // rows d, stride T_

  const int wrow_lo = q0 + wave * 32;

  // Q fragments (B-operand rows = qrow); Q already carries log2e/32
  bfrag qfr[2][2];
#pragma unroll
  for (int j = 0; j < 2; ++j)
#pragma unroll
    for (int ks = 0; ks < 2; ++ks)
      qfr[j][ks] = *(const bfrag*)(Qbase + (size_t)(wrow_lo + j * 16 + l15) * NDIM + ks * 32 + quad * 8);

  float l_st[2] = {0.f, 0.f};
  f32x4 o_acc[2][4] = {};
  short* pw = &Ps[wave][0];

  for (int kv0 = 0; kv0 < q0 + 128; kv0 += 128) {
    // stage K [128 keys][64 c] and V^T [2][64 d][64 keys], one burst, async
#pragma unroll
    for (int i = 0; i < 4; ++i) {
      int p0 = (wave * 4 + i) * 64;
      int p = p0 + lane;
      int kr = p >> 3, kcl = (p & 7) ^ (kr & 7);
      async_load16(Kbase + (size_t)(kv0 + kr) * NDIM + kcl * 8, (char*)Ks + p0 * 16);
      int hh = p >> 9, d = (p >> 3) & 63, vcl = (p & 7) ^ (d & 7);
      async_load16(Vbase + (size_t)d * T_ + kv0 + hh * 64 + vcl * 8, (char*)Vt + p0 * 16);
    }
    __syncthreads();

#pragma unroll
    for (int hf = 0; hf < 2; ++hf) {
      const int kvh = kv0 + hf * 64;
      if (kvh > wrow_lo + 31) break;

      // S^T = K * Q^T : sv[j][i], row key=i*16+quad*4+r (local), col qrow=j*16+l15
      f32x4 sv[2][4] = {};
#pragma unroll
      for (int ks = 0; ks < 2; ++ks) {
        bfrag kf[4];
#pragma unroll
        for (int i = 0; i < 4; ++i) {
          int key = i * 16 + l15;
          int c = (ks * 4 + quad) ^ (key & 7);
          kf[i] = *(const bfrag*)(Ks + (hf * 64 + key) * 64 + c * 8);
        }
#pragma unroll
        for (int j = 0; j < 2; ++j)
#pragma unroll
          for (int i = 0; i < 4; ++i)
            sv[j][i] = __builtin_amdgcn_mfma_f32_16x16x32_bf16(kf[i], qfr[j][ks], sv[j][i], 0, 0, 0);
      }

      // p = exp2(S) (scale pre-folded into Q); causal zeroing on diagonal only
#pragma unroll
      for (int j = 0; j < 2; ++j)
#pragma unroll
        for (int i = 0; i < 4; ++i)
#pragma unroll
          for (int r = 0; r < 4; ++r)
            sv[j][i][r] = __builtin_amdgcn_exp2f(sv[j][i][r]);
      if (kvh + 63 > wrow_lo) {
#pragma unroll
        for (int j = 0; j < 2; ++j) {
          int qr = wrow_lo + j * 16 + l15;
#pragma unroll
          for (int i = 0; i < 4; ++i) {
            int keyb = kvh + i * 16 + quad * 4;
#pragma unroll
            for (int r = 0; r < 4; ++r)
              if (keyb + r > qr) sv[j][i][r] = 0.f;
          }
        }
      }

      // l partials (keys in-lane) + packed P store (v_cvt_pk_bf16_f32)
#pragma unroll
      for (int j = 0; j < 2; ++j) {
#pragma unroll
        for (int i = 0; i < 4; ++i) {
          l_st[j] += sv[j][i][0] + sv[j][i][1] + sv[j][i][2] + sv[j][i][3];
          uint2 pk;
          pk.x = cvt_pk_bf16(sv[j][i][0], sv[j][i][1]);
          pk.y = cvt_pk_bf16(sv[j][i][2], sv[j][i][3]);
          *(uint2*)(pw + (j * 16 + l15) * 72 + i * 16 + quad * 4) = pk;
        }
      }

      // O^T += V^T * P^T
#pragma unroll
      for (int ks = 0; ks < 2; ++ks) {
        bfrag vf[4], pf[2];
#pragma unroll
        for (int i2 = 0; i2 < 4; ++i2) {
          int d = i2 * 16 + l15;
          int c = (ks * 4 + quad) ^ (d & 7);
          vf[i2] = *(const bfrag*)(&Vt[hf][0] + d * 64 + c * 8);
        }
#pragma unroll
        for (int j = 0; j < 2; ++j)
          pf[j] = *(const bfrag*)(pw + (j * 16 + l15) * 72 + ks * 32 + quad * 8);
#pragma unroll
        for (int j = 0; j < 2; ++j)
#pragma unroll
          for (int i2 = 0; i2 < 4; ++i2)
            o_acc[j][i2] = __builtin_amdgcn_mfma_f32_16x16x32_bf16(vf[i2], pf[j], o_acc[j][i2], 0, 0, 0);
      }
    }
    __syncthreads();
  }

  // epilogue: reduce l over quad groups, scale, write packed b64
#pragma unroll
  for (int j = 0; j < 2; ++j) {
    float s = l_st[j];
    s += __shfl_xor(s, 16, 64);
    s += __shfl_xor(s, 32, 64);
    float inv = 1.f / s;
    int qr = q0 + wave * 32 + j * 16 + l15;
    size_t base = ((size_t)b * T_ + qr) * NDIM + h * 64;
#pragma unroll
    for (int i2 = 0; i2 < 4; ++i2) {
      uint2 pk;
      pk.x = cvt_pk_bf16(o_acc[j][i2][0] * inv, o_acc[j][i2][1] * inv);
      pk.y = cvt_pk_bf16(o_acc[j][i2][2] * inv, o_acc[j][i2][3] * inv);
      *(uint2*)(Oh + base + i2 * 16 + quad * 4) = pk;
    }
  }
}

extern "C" void kernel_launch(void* const* d_in, const int* in_sizes, int n_in,
                              void* d_out, int out_size, void* d_ws, size_t ws_size,
                              hipStream_t stream)
{
  const float* q  = (const float*)d_in[0];
  const float* k  = (const float*)d_in[1];
  const float* v  = (const float*)d_in[2];
  const float* Wq = (const float*)d_in[3];
  const float* Wk = (const float*)d_in[4];
  const float* Wv = (const float*)d_in[5];
  const float* Wo = (const float*)d_in[6];
  const float* bo = (const float*)d_in[7];
  float* out = (float*)d_out;

  char* w = (char*)d_ws;
  const size_t szBTC = (size_t)MROWS * C_ * 2;   // 16 MB
  const size_t szW   = (size_t)NDIM * C_ * 2;    // 2 MB
  unsigned short* qb   = (unsigned short*)(w);
  unsigned short* kb   = (unsigned short*)(w + szBTC);
  unsigned short* vb   = (unsigned short*)(w + 2 * szBTC);
  unsigned short* wqT  = (unsigned short*)(w + 3 * szBTC);
  unsigned short* wkT  = (unsigned short*)(w + 3 * szBTC + szW);
  unsigned short* wvT  = (unsigned short*)(w + 3 * szBTC + 2 * szW);
  unsigned short* woT  = (unsigned short*)(w + 3 * szBTC + 3 * szW);
  unsigned short* qhp  = (unsigned short*)(w + 3 * szBTC + 4 * szW);
  unsigned short* khp  = (unsigned short*)(w + 4 * szBTC + 4 * szW);
  unsigned short* vT   = (unsigned short*)(w + 5 * szBTC + 4 * szW);  // [B][H][64][T]
  unsigned short* attO = (unsigned short*)(w + 6 * szBTC + 4 * szW);

  prep_kernel<<<dim3(25600), 256, 0, stream>>>(q, k, v, qb, kb, vb,
                                               Wq, Wk, Wv, wqT, wkT, wvT, Wo, woT);

  // Q,K,V projections: 256x128-tile 2-phase GEMM, 768 blocks
  gemm_bt2<0><<<dim3(768), 512, 0, stream>>>(
      qb, kb, vb, wqT, wkT, wvT, qhp, khp, vT, nullptr);

  flash_kernel<<<dim3(1024), 256, 0, stream>>>(qhp, khp, vT, attO);

  // output projection: 256 blocks = 1 exact round
  gemm_bt2<1><<<dim3(256), 512, 0, stream>>>(
      attO, attO, attO, woT, woT, woT, out, out, out, bo);
}